// Round 2
// baseline (563.890 us; speedup 1.0000x reference)
//
#include <hip/hip_runtime.h>
#include <hip/hip_bf16.h>
#include <cmath>

// Problem constants (fixed by the reference's setup_inputs)
#define BS 4
#define NP 8192
#define FD 512
#define SM 2048

// GEMM tiling
#define BM 128
#define BN 64
#define BK 32
#define TM 8
#define TN 4
#define NCT (SM / BN)  // 32 col tiles per batch row

// ---------------------------------------------------------------------------
// Kernel 1: per-match stats — d_pos (cosine sim) and anchor point (+ |p|^2)
// grid = BS*SM blocks, 128 threads (FD/4 float4 per row)
// ---------------------------------------------------------------------------
__global__ __launch_bounds__(128) void stats_k(
    const float* __restrict__ velo_feat, const float* __restrict__ velo_pts,
    const float* __restrict__ ref_feat, const int* __restrict__ matches,
    float4* __restrict__ pts4, float* __restrict__ dpos)
{
  const int bsS = blockIdx.x;          // b*SM + s
  const int b = bsS / SM;
  const int ai = matches[2 * bsS + 0];
  const int pi = matches[2 * bsS + 1];
  const int t = threadIdx.x;

  const float4* ar = (const float4*)(velo_feat + ((size_t)b * NP + ai) * FD);
  const float4* pr = (const float4*)(ref_feat + ((size_t)b * NP + pi) * FD);
  float4 av = ar[t];
  float4 pv = pr[t];

  float dot = av.x * pv.x + av.y * pv.y + av.z * pv.z + av.w * pv.w;
  float na = av.x * av.x + av.y * av.y + av.z * av.z + av.w * av.w;
  float nb = pv.x * pv.x + pv.y * pv.y + pv.z * pv.z + pv.w * pv.w;

#pragma unroll
  for (int off = 32; off; off >>= 1) {
    dot += __shfl_down(dot, off);
    na += __shfl_down(na, off);
    nb += __shfl_down(nb, off);
  }
  __shared__ float red[2][3];
  if ((t & 63) == 0) {
    red[t >> 6][0] = dot;
    red[t >> 6][1] = na;
    red[t >> 6][2] = nb;
  }
  __syncthreads();
  if (t == 0) {
    dot = red[0][0] + red[1][0];
    na = red[0][1] + red[1][1];
    nb = red[0][2] + red[1][2];
    float d = dot / fmaxf(sqrtf(na) * sqrtf(nb), 1e-8f);
    dpos[bsS] = d;
    const float* pp = velo_pts + ((size_t)b * NP + ai) * 3;
    float x = pp[0], y = pp[1], z = pp[2];
    pts4[bsS] = make_float4(x, y, z, x * x + y * y + z * z);
  }
}

// ---------------------------------------------------------------------------
// Kernel 2: fused GEMM tile + distance mask + streaming LSE partials
// grid = (SM/BM, NCT, BS), 256 threads; block owns rows [s0,s0+128) x cols
// [c0,c0+64); writes maxs/sums[ctile][b][s] (exclusive -> deterministic)
// ---------------------------------------------------------------------------
__global__ __launch_bounds__(256) void tile_k(
    const float* __restrict__ velo_feat, const float* __restrict__ ref_feat,
    const int* __restrict__ matches, const float4* __restrict__ pts4,
    float* __restrict__ maxs, float* __restrict__ sums)
{
  __shared__ __align__(16) float As[BK][BM + 4];  // stride 132 floats
  __shared__ __align__(16) float Bs[BK][BN + 4];  // stride 68 floats
  __shared__ float4 rp[BM];
  __shared__ float4 cp[BN];
  __shared__ int aidx[BM];
  __shared__ int bidx[BN];

  const int stile = blockIdx.x, ctile = blockIdx.y, b = blockIdx.z;
  const int s0 = stile * BM, c0 = ctile * BN;
  const int tid = threadIdx.x;
  const int tx = tid & 15, ty = tid >> 4;

  if (tid < BM) {
    aidx[tid] = matches[((size_t)b * SM + s0 + tid) * 2];
    rp[tid] = pts4[(size_t)b * SM + s0 + tid];
  }
  if (tid < BN) {
    bidx[tid] = matches[((size_t)b * SM + c0 + tid) * 2 + 1];
    cp[tid] = pts4[(size_t)b * SM + c0 + tid];
  }

  const float* Abase = velo_feat + (size_t)b * NP * FD;
  const float* Bbase = ref_feat + (size_t)b * NP * FD;

  float acc[TM][TN];
#pragma unroll
  for (int i = 0; i < TM; i++)
#pragma unroll
    for (int j = 0; j < TN; j++) acc[i][j] = 0.f;

  for (int kk = 0; kk < FD; kk += BK) {
    __syncthreads();  // also orders aidx/bidx/rp/cp writes before first use
    // stage A: 128 rows x 32 k = 1024 float4, 4 per thread (transposed write)
#pragma unroll
    for (int i = 0; i < 4; i++) {
      int idx = tid + i * 256;
      int row = idx >> 3, fc = (idx & 7) * 4;
      float4 v = *(const float4*)(Abase + (size_t)aidx[row] * FD + kk + fc);
      As[fc + 0][row] = v.x;
      As[fc + 1][row] = v.y;
      As[fc + 2][row] = v.z;
      As[fc + 3][row] = v.w;
    }
    // stage B: 64 rows x 32 k = 512 float4, 2 per thread
#pragma unroll
    for (int i = 0; i < 2; i++) {
      int idx = tid + i * 256;
      int row = idx >> 3, fc = (idx & 7) * 4;
      float4 v = *(const float4*)(Bbase + (size_t)bidx[row] * FD + kk + fc);
      Bs[fc + 0][row] = v.x;
      Bs[fc + 1][row] = v.y;
      Bs[fc + 2][row] = v.z;
      Bs[fc + 3][row] = v.w;
    }
    __syncthreads();
#pragma unroll
    for (int k = 0; k < BK; k++) {
      float4 a0 = *(const float4*)&As[k][ty * TM];
      float4 a1 = *(const float4*)&As[k][ty * TM + 4];
      float4 bv = *(const float4*)&Bs[k][tx * TN];
      float a[TM] = {a0.x, a0.y, a0.z, a0.w, a1.x, a1.y, a1.z, a1.w};
      float bb[TN] = {bv.x, bv.y, bv.z, bv.w};
#pragma unroll
      for (int i = 0; i < TM; i++)
#pragma unroll
        for (int j = 0; j < TN; j++) acc[i][j] = fmaf(a[i], bb[j], acc[i][j]);
    }
  }

  // epilogue: masked logits -> per-row (max, sum(exp(l-max))) partials.
  // Stable: never materializes exp(D/tau) unscaled (that overflows f32).
#pragma unroll
  for (int i = 0; i < TM; i++) {
    float4 r = rp[ty * TM + i];
#pragma unroll
    for (int j = 0; j < TN; j++) {
      float4 c = cp[tx * TN + j];
      float d2 = r.w + c.w - 2.f * (r.x * c.x + r.y * c.y + r.z * c.z);
      acc[i][j] = (d2 > 25.f) ? acc[i][j] / 0.1f : -INFINITY;
    }
  }
  float rowmax[TM], rowsum[TM];
#pragma unroll
  for (int i = 0; i < TM; i++) {
    float m = fmaxf(fmaxf(acc[i][0], acc[i][1]), fmaxf(acc[i][2], acc[i][3]));
#pragma unroll
    for (int off = 8; off; off >>= 1) m = fmaxf(m, __shfl_xor(m, off, 16));
    rowmax[i] = m;  // -inf only if ALL 64 cols masked (then sum stays 0)
    float s = 0.f;
#pragma unroll
    for (int j = 0; j < TN; j++)
      s += (acc[i][j] == -INFINITY) ? 0.f : expf(acc[i][j] - m);
#pragma unroll
    for (int off = 8; off; off >>= 1) s += __shfl_xor(s, off, 16);
    rowsum[i] = s;
  }
  if (tx == 0) {
    size_t base = ((size_t)ctile * BS + b) * SM + s0 + ty * TM;
#pragma unroll
    for (int i = 0; i < TM; i++) {
      maxs[base + i] = rowmax[i];
      sums[base + i] = rowsum[i];
    }
  }
}

// ---------------------------------------------------------------------------
// Kernel 3: merge LSE partials + d_pos term, loss + mean (1 block, f64 acc)
// loss_row = M + log(exp(l0-M) + sum_c s_c*exp(m_c-M)) - l0   (always finite)
// ---------------------------------------------------------------------------
__global__ __launch_bounds__(256) void final_k(
    const float* __restrict__ dpos, const float* __restrict__ maxs,
    const float* __restrict__ sums, float* __restrict__ out)
{
  const int tid = threadIdx.x;
  double sum = 0.0;
  for (int r = tid; r < BS * SM; r += 256) {
    float l0 = dpos[r] / 0.1f;
    float M = l0;
    for (int c = 0; c < NCT; c++)
      M = fmaxf(M, maxs[(size_t)c * BS * SM + r]);
    float s = expf(l0 - M);
    for (int c = 0; c < NCT; c++) {
      float mc = maxs[(size_t)c * BS * SM + r];
      float sc = sums[(size_t)c * BS * SM + r];
      s += (mc == -INFINITY) ? 0.f : sc * expf(mc - M);
    }
    sum += (double)(M + logf(s) - l0);
  }
#pragma unroll
  for (int off = 32; off; off >>= 1) sum += __shfl_down(sum, off);
  __shared__ double red[4];
  if ((tid & 63) == 0) red[tid >> 6] = sum;
  __syncthreads();
  if (tid == 0)
    out[0] = (float)((red[0] + red[1] + red[2] + red[3]) / (double)(BS * SM));
}

// ---------------------------------------------------------------------------
extern "C" void kernel_launch(void* const* d_in, const int* in_sizes, int n_in,
                              void* d_out, int out_size, void* d_ws, size_t ws_size,
                              hipStream_t stream)
{
  const float* velo_feat = (const float*)d_in[0];
  const float* velo_pts  = (const float*)d_in[1];
  const float* ref_feat  = (const float*)d_in[2];
  const int*   matches   = (const int*)d_in[3];

  // workspace layout (16B-aligned): pts4 | dpos | maxs | sums  (~2.2 MB)
  char* ws = (char*)d_ws;
  float4* pts4 = (float4*)ws;                                    // 131072 B
  float*  dpos = (float*)(ws + (size_t)BS * SM * 16);            //  32768 B
  float*  maxs = (float*)(ws + (size_t)BS * SM * 20);            // 1 MB
  float*  sums = (float*)(ws + (size_t)BS * SM * 20 + (size_t)NCT * BS * SM * 4);

  stats_k<<<BS * SM, 128, 0, stream>>>(velo_feat, velo_pts, ref_feat, matches,
                                       pts4, dpos);
  tile_k<<<dim3(SM / BM, NCT, BS), 256, 0, stream>>>(velo_feat, ref_feat,
                                                     matches, pts4, maxs, sums);
  final_k<<<1, 256, 0, stream>>>(dpos, maxs, sums, (float*)d_out);
}

// Round 3
// 91.061 us; speedup vs baseline: 6.1924x; 6.1924x over previous
//
#include <hip/hip_runtime.h>
#include <hip/hip_bf16.h>
#include <cmath>

#define BS 4
#define NP 8192
#define FD 512
#define SM 2048

typedef __attribute__((ext_vector_type(8))) short short8;
typedef __attribute__((ext_vector_type(4))) float f32x4;

static __device__ __forceinline__ unsigned short f2bf(float f) {
  unsigned u = __float_as_uint(f);
  unsigned r = u + 0x7fffu + ((u >> 16) & 1u);  // RTNE (inputs are normal floats)
  return (unsigned short)(r >> 16);
}

// ---------------------------------------------------------------------------
// Kernel 1: gather + cosine-sim + anchor pts (+|p|^2) + bf16 row copies
// grid = BS*SM blocks, 128 threads
// ---------------------------------------------------------------------------
__global__ __launch_bounds__(128) void stats_k(
    const float* __restrict__ velo_feat, const float* __restrict__ velo_pts,
    const float* __restrict__ ref_feat, const int* __restrict__ matches,
    float4* __restrict__ pts4, float* __restrict__ dpos,
    unsigned short* __restrict__ Abf, unsigned short* __restrict__ Pbf)
{
  const int bsS = blockIdx.x;  // b*SM + s
  const int b = bsS / SM;
  const int ai = matches[2 * bsS + 0];
  const int pi = matches[2 * bsS + 1];
  const int t = threadIdx.x;

  const float4* ar = (const float4*)(velo_feat + ((size_t)b * NP + ai) * FD);
  const float4* pr = (const float4*)(ref_feat + ((size_t)b * NP + pi) * FD);
  float4 av = ar[t];
  float4 pv = pr[t];

  // bf16 copies (contiguous, per-match layout) for the MFMA GEMM
  ushort4 a16, p16;
  a16.x = f2bf(av.x); a16.y = f2bf(av.y); a16.z = f2bf(av.z); a16.w = f2bf(av.w);
  p16.x = f2bf(pv.x); p16.y = f2bf(pv.y); p16.z = f2bf(pv.z); p16.w = f2bf(pv.w);
  *(ushort4*)(Abf + (size_t)bsS * FD + t * 4) = a16;
  *(ushort4*)(Pbf + (size_t)bsS * FD + t * 4) = p16;

  float dot = av.x * pv.x + av.y * pv.y + av.z * pv.z + av.w * pv.w;
  float na = av.x * av.x + av.y * av.y + av.z * av.z + av.w * av.w;
  float nb = pv.x * pv.x + pv.y * pv.y + pv.z * pv.z + pv.w * pv.w;

#pragma unroll
  for (int off = 32; off; off >>= 1) {
    dot += __shfl_down(dot, off);
    na += __shfl_down(na, off);
    nb += __shfl_down(nb, off);
  }
  __shared__ float red[2][3];
  if ((t & 63) == 0) {
    red[t >> 6][0] = dot; red[t >> 6][1] = na; red[t >> 6][2] = nb;
  }
  __syncthreads();
  if (t == 0) {
    dot = red[0][0] + red[1][0];
    na = red[0][1] + red[1][1];
    nb = red[0][2] + red[1][2];
    dpos[bsS] = dot / fmaxf(sqrtf(na) * sqrtf(nb), 1e-8f);
    const float* pp = velo_pts + ((size_t)b * NP + ai) * 3;
    float x = pp[0], y = pp[1], z = pp[2];
    pts4[bsS] = make_float4(x, y, z, x * x + y * y + z * z);
  }
}

// ---------------------------------------------------------------------------
// Kernel 2: MFMA bf16 GEMM (128x128 tile) + mask + streaming LSE partials
// grid = (16 ctile, 16 stile, BS), 256 threads (4 waves of 64x64).
// Partial layout: 32 col-chunks of 64 -> maxs/sums[ct32][b][s]
// ---------------------------------------------------------------------------
__global__ __launch_bounds__(256) void tile_k(
    const unsigned short* __restrict__ Abf, const unsigned short* __restrict__ Pbf,
    const float4* __restrict__ pts4,
    float* __restrict__ maxs, float* __restrict__ sums)
{
  __shared__ unsigned short As[128][72];  // row stride 144B (16B-aligned, bank-rotated)
  __shared__ unsigned short Bs[128][72];
  __shared__ float4 rp[128];
  __shared__ float4 cp[128];

  const int ctile = blockIdx.x, stile = blockIdx.y, b = blockIdx.z;
  const int s0 = stile * 128, c0 = ctile * 128;
  const int tid = threadIdx.x;
  const int wid = tid >> 6, lane = tid & 63;
  const int wr = wid >> 1, wc = wid & 1;   // wave -> 64x64 quadrant
  const int cg = lane >> 4, cr = lane & 15;

  if (tid < 128) rp[tid] = pts4[(size_t)b * SM + s0 + tid];
  else           cp[tid - 128] = pts4[(size_t)b * SM + c0 + (tid - 128)];

  const unsigned short* Ab = Abf + ((size_t)b * SM + s0) * FD;
  const unsigned short* Bb = Pbf + ((size_t)b * SM + c0) * FD;
  const int srow = tid >> 1, shalf = tid & 1;  // 2 threads/row, 64B each

  f32x4 acc[4][4];
#pragma unroll
  for (int m = 0; m < 4; m++)
#pragma unroll
    for (int n = 0; n < 4; n++) acc[m][n] = (f32x4){0.f, 0.f, 0.f, 0.f};

  for (int kk = 0; kk < FD; kk += 64) {
    __syncthreads();
    const unsigned short* asrc = Ab + (size_t)srow * FD + kk + shalf * 32;
    const unsigned short* bsrc = Bb + (size_t)srow * FD + kk + shalf * 32;
    uint4 avv[4], bvv[4];
#pragma unroll
    for (int j = 0; j < 4; j++) avv[j] = *(const uint4*)(asrc + j * 8);
#pragma unroll
    for (int j = 0; j < 4; j++) bvv[j] = *(const uint4*)(bsrc + j * 8);
#pragma unroll
    for (int j = 0; j < 4; j++) *(uint4*)&As[srow][shalf * 32 + j * 8] = avv[j];
#pragma unroll
    for (int j = 0; j < 4; j++) *(uint4*)&Bs[srow][shalf * 32 + j * 8] = bvv[j];
    __syncthreads();

#pragma unroll
    for (int ks = 0; ks < 2; ks++) {
      short8 af[4], bf[4];
#pragma unroll
      for (int m = 0; m < 4; m++)
        af[m] = *(const short8*)&As[wr * 64 + m * 16 + cr][ks * 32 + cg * 8];
#pragma unroll
      for (int n = 0; n < 4; n++)
        bf[n] = *(const short8*)&Bs[wc * 64 + n * 16 + cr][ks * 32 + cg * 8];
#pragma unroll
      for (int m = 0; m < 4; m++)
#pragma unroll
        for (int n = 0; n < 4; n++)
          acc[m][n] = __builtin_amdgcn_mfma_f32_16x16x32_bf16(af[m], bf[n],
                                                              acc[m][n], 0, 0, 0);
    }
  }

  // epilogue: C/D map col=lane&15, row=(lane>>4)*4+reg  [m89-verified]
  const int ct32 = ctile * 2 + wc;
  float4 cv[4];
#pragma unroll
  for (int n = 0; n < 4; n++) cv[n] = cp[wc * 64 + n * 16 + cr];

#pragma unroll
  for (int m = 0; m < 4; m++) {
#pragma unroll
    for (int r = 0; r < 4; r++) {
      const int rit = wr * 64 + m * 16 + cg * 4 + r;
      float4 rv = rp[rit];
      float l[4];
      float vmax = -INFINITY;
#pragma unroll
      for (int n = 0; n < 4; n++) {
        float d2 = rv.w + cv[n].w -
                   2.f * (rv.x * cv[n].x + rv.y * cv[n].y + rv.z * cv[n].z);
        float logit = acc[m][n][r] * 10.f;
        l[n] = (d2 > 25.f) ? logit : -INFINITY;
        vmax = fmaxf(vmax, l[n]);
      }
#pragma unroll
      for (int off = 1; off < 16; off <<= 1)
        vmax = fmaxf(vmax, __shfl_xor(vmax, off, 16));
      float vs = 0.f;
#pragma unroll
      for (int n = 0; n < 4; n++)
        vs += (l[n] == -INFINITY) ? 0.f : expf(l[n] - vmax);
#pragma unroll
      for (int off = 1; off < 16; off <<= 1) vs += __shfl_xor(vs, off, 16);
      if (cr == 0) {
        size_t base = ((size_t)ct32 * BS + b) * SM + s0 + rit;
        maxs[base] = vmax;
        sums[base] = vs;
      }
    }
  }
}

// ---------------------------------------------------------------------------
// Kernel 3: per-row LSE merge + loss (parallel over rows)
// ---------------------------------------------------------------------------
__global__ __launch_bounds__(256) void rowloss_k(
    const float* __restrict__ dpos, const float* __restrict__ maxs,
    const float* __restrict__ sums, float* __restrict__ loss)
{
  const int r = blockIdx.x * 256 + threadIdx.x;  // 0 .. BS*SM-1
  float l0 = dpos[r] * 10.f;
  float M = l0;
#pragma unroll 8
  for (int c = 0; c < 32; c++) M = fmaxf(M, maxs[(size_t)c * BS * SM + r]);
  float s = expf(l0 - M);
#pragma unroll 8
  for (int c = 0; c < 32; c++) {
    float mc = maxs[(size_t)c * BS * SM + r];
    float sc = sums[(size_t)c * BS * SM + r];
    s += (mc == -INFINITY) ? 0.f : sc * expf(mc - M);
  }
  loss[r] = M + logf(s) - l0;
}

// ---------------------------------------------------------------------------
// Kernel 4: mean (1 block, f64 accumulate)
// ---------------------------------------------------------------------------
__global__ __launch_bounds__(256) void reduce_k(const float* __restrict__ loss,
                                               float* __restrict__ out)
{
  double acc = 0.0;
  for (int i = threadIdx.x; i < BS * SM; i += 256) acc += (double)loss[i];
#pragma unroll
  for (int off = 32; off; off >>= 1) acc += __shfl_down(acc, off);
  __shared__ double red[4];
  if ((threadIdx.x & 63) == 0) red[threadIdx.x >> 6] = acc;
  __syncthreads();
  if (threadIdx.x == 0)
    out[0] = (float)((red[0] + red[1] + red[2] + red[3]) / (double)(BS * SM));
}

// ---------------------------------------------------------------------------
extern "C" void kernel_launch(void* const* d_in, const int* in_sizes, int n_in,
                              void* d_out, int out_size, void* d_ws, size_t ws_size,
                              hipStream_t stream)
{
  const float* velo_feat = (const float*)d_in[0];
  const float* velo_pts  = (const float*)d_in[1];
  const float* ref_feat  = (const float*)d_in[2];
  const int*   matches   = (const int*)d_in[3];

  // ws layout (16B aligned): Abf | Pbf | pts4 | dpos | maxs | sums | loss
  char* ws = (char*)d_ws;
  const size_t NBF = (size_t)BS * SM * FD * 2;     // 8 MB each
  unsigned short* Abf = (unsigned short*)ws;
  unsigned short* Pbf = (unsigned short*)(ws + NBF);
  float4* pts4 = (float4*)(ws + 2 * NBF);                          // 128 KB
  float*  dpos = (float*)(ws + 2 * NBF + (size_t)BS * SM * 16);    //  32 KB
  float*  maxs = (float*)(ws + 2 * NBF + (size_t)BS * SM * 20);    //   1 MB
  float*  sums = (float*)(ws + 2 * NBF + (size_t)BS * SM * 20 + (size_t)32 * BS * SM * 4);
  float*  loss = (float*)(ws + 2 * NBF + (size_t)BS * SM * 20 + (size_t)64 * BS * SM * 4);

  stats_k<<<BS * SM, 128, 0, stream>>>(velo_feat, velo_pts, ref_feat, matches,
                                       pts4, dpos, Abf, Pbf);
  tile_k<<<dim3(16, 16, BS), 256, 0, stream>>>(Abf, Pbf, pts4, maxs, sums);
  rowloss_k<<<BS * SM / 256, 256, 0, stream>>>(dpos, maxs, sums, loss);
  reduce_k<<<1, 256, 0, stream>>>(loss, (float*)d_out);
}

// Round 5
// 76.523 us; speedup vs baseline: 7.3689x; 1.1900x over previous
//
#include <hip/hip_runtime.h>
#include <hip/hip_bf16.h>
#include <cmath>

#define BS 4
#define NP 8192
#define FD 512
#define SM 2048
#define LOG2E10 14.4269504088896340736f  // 10 * log2(e)  (tau=0.1 folded)
#define LN2 0.6931471805599453f

typedef __attribute__((ext_vector_type(8))) short short8;
typedef __attribute__((ext_vector_type(4))) float f32x4;

static __device__ __forceinline__ unsigned short f2bf(float f) {
  unsigned u = __float_as_uint(f);
  unsigned r = u + 0x7fffu + ((u >> 16) & 1u);  // RTNE
  return (unsigned short)(r >> 16);
}
static __device__ __forceinline__ ushort4 f2bf4(float4 v) {
  ushort4 o;
  o.x = f2bf(v.x); o.y = f2bf(v.y); o.z = f2bf(v.z); o.w = f2bf(v.w);
  return o;
}

// ---------------------------------------------------------------------------
// Kernel 1: 1 wave per match row — gather, cos-sim, pts(+|p|^2), bf16 copies
// grid = BS*SM/4 blocks x 256 (4 waves/block), no LDS, shfl-only reduce
// ---------------------------------------------------------------------------
__global__ __launch_bounds__(256) void stats_k(
    const float* __restrict__ velo_feat, const float* __restrict__ velo_pts,
    const float* __restrict__ ref_feat, const int* __restrict__ matches,
    float4* __restrict__ pts4, float* __restrict__ dpos,
    unsigned short* __restrict__ Abf, unsigned short* __restrict__ Pbf)
{
  const int row = blockIdx.x * 4 + (threadIdx.x >> 6);  // b*SM + s
  const int lane = threadIdx.x & 63;
  const int b = row >> 11;  // / SM
  const int ai = matches[2 * row + 0];
  const int pi = matches[2 * row + 1];

  const float4* ar = (const float4*)(velo_feat + ((size_t)b * NP + ai) * FD);
  const float4* pr = (const float4*)(ref_feat + ((size_t)b * NP + pi) * FD);
  float4 a0 = ar[lane], a1 = ar[lane + 64];
  float4 p0 = pr[lane], p1 = pr[lane + 64];

  *(ushort4*)(Abf + (size_t)row * FD + lane * 4) = f2bf4(a0);
  *(ushort4*)(Abf + (size_t)row * FD + 256 + lane * 4) = f2bf4(a1);
  *(ushort4*)(Pbf + (size_t)row * FD + lane * 4) = f2bf4(p0);
  *(ushort4*)(Pbf + (size_t)row * FD + 256 + lane * 4) = f2bf4(p1);

  float dot = a0.x * p0.x + a0.y * p0.y + a0.z * p0.z + a0.w * p0.w +
              a1.x * p1.x + a1.y * p1.y + a1.z * p1.z + a1.w * p1.w;
  float na = a0.x * a0.x + a0.y * a0.y + a0.z * a0.z + a0.w * a0.w +
             a1.x * a1.x + a1.y * a1.y + a1.z * a1.z + a1.w * a1.w;
  float nb = p0.x * p0.x + p0.y * p0.y + p0.z * p0.z + p0.w * p0.w +
             p1.x * p1.x + p1.y * p1.y + p1.z * p1.z + p1.w * p1.w;
#pragma unroll
  for (int off = 32; off; off >>= 1) {
    dot += __shfl_xor(dot, off);
    na += __shfl_xor(na, off);
    nb += __shfl_xor(nb, off);
  }
  if (lane == 0) {
    dpos[row] = dot / fmaxf(sqrtf(na) * sqrtf(nb), 1e-8f);
    const float* pp = velo_pts + ((size_t)b * NP + ai) * 3;
    float x = pp[0], y = pp[1], z = pp[2];
    pts4[row] = make_float4(x, y, z, x * x + y * y + z * z);
  }
}

// ---------------------------------------------------------------------------
// Kernel 2: MFMA bf16 GEMM 128x128, global_load_lds(16B) staging, linear LDS
// + both-sides XOR swizzle (LDS[row,c] = G[row, c^((row&7)<<4)]); fused
// mask + streaming-LSE epilogue. grid = (16,16,BS) x 256 (4 waves, 64x64 each)
// ---------------------------------------------------------------------------
__global__ __launch_bounds__(256) void tile_k(
    const unsigned short* __restrict__ Abf, const unsigned short* __restrict__ Pbf,
    const float4* __restrict__ pts4,
    float* __restrict__ maxs, float* __restrict__ sums)
{
  __shared__ unsigned short As[128 * 64];  // linear, row = 128 B
  __shared__ unsigned short Bs[128 * 64];
  __shared__ float4 rp[128];
  __shared__ float4 cp[128];

  const int ctile = blockIdx.x, stile = blockIdx.y, b = blockIdx.z;
  const int s0 = stile * 128, c0 = ctile * 128;
  const int tid = threadIdx.x;
  const int wid = tid >> 6, lane = tid & 63;
  const int wr = wid >> 1, wc = wid & 1;  // wave -> 64x64 quadrant
  const int cg = lane >> 4, cr = lane & 15;

  if (tid < 128) rp[tid] = pts4[(size_t)b * SM + s0 + tid];
  else           cp[tid - 128] = pts4[(size_t)b * SM + c0 + (tid - 128)];

  const char* Ab = (const char*)(Abf + ((size_t)b * SM + s0) * FD);
  const char* Bb = (const char*)(Pbf + ((size_t)b * SM + c0) * FD);

  // per-lane staging geometry (loop-invariant): chunk covers 8 rows x 128 B
  int srow[4], soff[4];
#pragma unroll
  for (int i = 0; i < 4; i++) {
    const int L = (wid * 4 + i) * 1024 + lane * 16;  // byte within 16 KB tile
    srow[i] = L >> 7;
    const int c = L & 127;
    soff[i] = c ^ ((srow[i] & 7) << 4);  // inverse swizzle on global source
  }

  f32x4 acc[4][4];
#pragma unroll
  for (int m = 0; m < 4; m++)
#pragma unroll
    for (int n = 0; n < 4; n++) acc[m][n] = (f32x4){0.f, 0.f, 0.f, 0.f};

  for (int kk = 0; kk < FD * 2; kk += 128) {  // kk = byte offset in row, BK=64
    __syncthreads();
#pragma unroll
    for (int i = 0; i < 4; i++) {
      const int chunk = wid * 4 + i;
      __builtin_amdgcn_global_load_lds(
          (const __attribute__((address_space(1))) void*)(Ab + (size_t)srow[i] * (FD * 2) + kk + soff[i]),
          (__attribute__((address_space(3))) void*)((char*)As + chunk * 1024),
          16, 0, 0);
      __builtin_amdgcn_global_load_lds(
          (const __attribute__((address_space(1))) void*)(Bb + (size_t)srow[i] * (FD * 2) + kk + soff[i]),
          (__attribute__((address_space(3))) void*)((char*)Bs + chunk * 1024),
          16, 0, 0);
    }
    __syncthreads();  // compiler drains vmcnt before barrier

#pragma unroll
    for (int ks = 0; ks < 2; ks++) {
      short8 af[4], bfr[4];
#pragma unroll
      for (int m = 0; m < 4; m++) {
        const int r = wr * 64 + m * 16 + cr;
        const int x = (ks * 64 + cg * 16) ^ ((r & 7) << 4);  // same swizzle on read
        af[m] = *(const short8*)((const char*)As + r * 128 + x);
      }
#pragma unroll
      for (int n = 0; n < 4; n++) {
        const int r = wc * 64 + n * 16 + cr;
        const int x = (ks * 64 + cg * 16) ^ ((r & 7) << 4);
        bfr[n] = *(const short8*)((const char*)Bs + r * 128 + x);
      }
#pragma unroll
      for (int m = 0; m < 4; m++)
#pragma unroll
        for (int n = 0; n < 4; n++)
          acc[m][n] = __builtin_amdgcn_mfma_f32_16x16x32_bf16(af[m], bfr[n],
                                                              acc[m][n], 0, 0, 0);
    }
  }

  // epilogue: C/D map col=lane&15, row=(lane>>4)*4+reg  [m89]
  const int ct32 = ctile * 2 + wc;
  float4 cv[4];
#pragma unroll
  for (int n = 0; n < 4; n++) cv[n] = cp[wc * 64 + n * 16 + cr];

#pragma unroll
  for (int m = 0; m < 4; m++) {
#pragma unroll
    for (int r = 0; r < 4; r++) {
      const int rit = wr * 64 + m * 16 + cg * 4 + r;
      float4 rv = rp[rit];
      float l[4];
      float vmax = -INFINITY;
#pragma unroll
      for (int n = 0; n < 4; n++) {
        float d2 = rv.w + cv[n].w -
                   2.f * (rv.x * cv[n].x + rv.y * cv[n].y + rv.z * cv[n].z);
        l[n] = (d2 > 25.f) ? acc[m][n][r] * LOG2E10 : -INFINITY;
        vmax = fmaxf(vmax, l[n]);
      }
#pragma unroll
      for (int off = 1; off < 16; off <<= 1)
        vmax = fmaxf(vmax, __shfl_xor(vmax, off, 16));
      float vs = 0.f;
#pragma unroll
      for (int n = 0; n < 4; n++)
        vs += (l[n] == -INFINITY) ? 0.f : exp2f(l[n] - vmax);
#pragma unroll
      for (int off = 1; off < 16; off <<= 1) vs += __shfl_xor(vs, off, 16);
      if (cr == 0) {
        size_t base = ((size_t)ct32 * BS + b) * SM + s0 + rit;
        maxs[base] = vmax;  // base-2 logit max
        sums[base] = vs;    // sum 2^(l-max)
      }
    }
  }
}

// ---------------------------------------------------------------------------
// Kernel 3: per-row LSE merge + loss, per-block f64 partial (32 blocks)
// ---------------------------------------------------------------------------
__global__ __launch_bounds__(256) void rowloss_k(
    const float* __restrict__ dpos, const float* __restrict__ maxs,
    const float* __restrict__ sums, double* __restrict__ partial)
{
  const int r = blockIdx.x * 256 + threadIdx.x;
  float l0 = dpos[r] * LOG2E10;
  float M = l0;
#pragma unroll 8
  for (int c = 0; c < 32; c++) M = fmaxf(M, maxs[(size_t)c * BS * SM + r]);
  float s = exp2f(l0 - M);
#pragma unroll 8
  for (int c = 0; c < 32; c++) {
    float mc = maxs[(size_t)c * BS * SM + r];
    float sc = sums[(size_t)c * BS * SM + r];
    s += (mc == -INFINITY) ? 0.f : sc * exp2f(mc - M);
  }
  double v = (double)(LN2 * (M + log2f(s) - l0));
#pragma unroll
  for (int off = 32; off; off >>= 1) v += __shfl_down(v, off);
  __shared__ double red[4];
  if ((threadIdx.x & 63) == 0) red[threadIdx.x >> 6] = v;
  __syncthreads();
  if (threadIdx.x == 0)
    partial[blockIdx.x] = red[0] + red[1] + red[2] + red[3];
}

// ---------------------------------------------------------------------------
// Kernel 4: final mean over 32 partials (1 tiny block)
// ---------------------------------------------------------------------------
__global__ __launch_bounds__(64) void final_k(const double* __restrict__ partial,
                                              float* __restrict__ out)
{
  const int t = threadIdx.x;
  double v = (t < 32) ? partial[t] : 0.0;
#pragma unroll
  for (int off = 32; off; off >>= 1) v += __shfl_down(v, off);
  if (t == 0) out[0] = (float)(v / (double)(BS * SM));
}

// ---------------------------------------------------------------------------
extern "C" void kernel_launch(void* const* d_in, const int* in_sizes, int n_in,
                              void* d_out, int out_size, void* d_ws, size_t ws_size,
                              hipStream_t stream)
{
  const float* velo_feat = (const float*)d_in[0];
  const float* velo_pts  = (const float*)d_in[1];
  const float* ref_feat  = (const float*)d_in[2];
  const int*   matches   = (const int*)d_in[3];

  // ws layout: Abf(8MB) | Pbf(8MB) | pts4(128K) | dpos(32K) | maxs(1M) | sums(1M) | partial
  char* ws = (char*)d_ws;
  const size_t NBF = (size_t)BS * SM * FD * 2;
  unsigned short* Abf = (unsigned short*)ws;
  unsigned short* Pbf = (unsigned short*)(ws + NBF);
  float4* pts4 = (float4*)(ws + 2 * NBF);
  float*  dpos = (float*)(ws + 2 * NBF + (size_t)BS * SM * 16);
  float*  maxs = (float*)(ws + 2 * NBF + (size_t)BS * SM * 20);
  float*  sums = (float*)(ws + 2 * NBF + (size_t)BS * SM * 20 + (size_t)32 * BS * SM * 4);
  double* partial = (double*)(ws + 2 * NBF + (size_t)BS * SM * 20 + (size_t)64 * BS * SM * 4);

  stats_k<<<BS * SM / 4, 256, 0, stream>>>(velo_feat, velo_pts, ref_feat,
                                           matches, pts4, dpos, Abf, Pbf);
  tile_k<<<dim3(16, 16, BS), 256, 0, stream>>>(Abf, Pbf, pts4, maxs, sums);
  rowloss_k<<<BS * SM / 256, 256, 0, stream>>>(dpos, maxs, sums, partial);
  final_k<<<1, 64, 0, stream>>>(partial, (float*)d_out);
}

// Round 6
// 73.416 us; speedup vs baseline: 7.6807x; 1.0423x over previous
//
#include <hip/hip_runtime.h>
#include <hip/hip_bf16.h>
#include <cmath>

#define BS 4
#define NP 8192
#define FD 512
#define SM 2048
#define LOG2E10 14.4269504088896340736f  // 10 * log2(e)  (tau=0.1 folded)
#define LN2 0.6931471805599453f

typedef __attribute__((ext_vector_type(8))) short short8;
typedef __attribute__((ext_vector_type(4))) float f32x4;

static __device__ __forceinline__ unsigned short f2bf(float f) {
  unsigned u = __float_as_uint(f);
  unsigned r = u + 0x7fffu + ((u >> 16) & 1u);  // RTNE
  return (unsigned short)(r >> 16);
}
static __device__ __forceinline__ ushort4 f2bf4(float4 v) {
  ushort4 o;
  o.x = f2bf(v.x); o.y = f2bf(v.y); o.z = f2bf(v.z); o.w = f2bf(v.w);
  return o;
}

// ---------------------------------------------------------------------------
// Kernel 1: 1 wave per match row — gather, cos-sim, pts(+|p|^2), bf16 copies
// ---------------------------------------------------------------------------
__global__ __launch_bounds__(256) void stats_k(
    const float* __restrict__ velo_feat, const float* __restrict__ velo_pts,
    const float* __restrict__ ref_feat, const int* __restrict__ matches,
    float4* __restrict__ pts4, float* __restrict__ dpos,
    unsigned short* __restrict__ Abf, unsigned short* __restrict__ Pbf)
{
  const int row = blockIdx.x * 4 + (threadIdx.x >> 6);  // b*SM + s
  const int lane = threadIdx.x & 63;
  const int b = row >> 11;  // / SM
  const int ai = matches[2 * row + 0];
  const int pi = matches[2 * row + 1];

  const float4* ar = (const float4*)(velo_feat + ((size_t)b * NP + ai) * FD);
  const float4* pr = (const float4*)(ref_feat + ((size_t)b * NP + pi) * FD);
  float4 a0 = ar[lane], a1 = ar[lane + 64];
  float4 p0 = pr[lane], p1 = pr[lane + 64];

  *(ushort4*)(Abf + (size_t)row * FD + lane * 4) = f2bf4(a0);
  *(ushort4*)(Abf + (size_t)row * FD + 256 + lane * 4) = f2bf4(a1);
  *(ushort4*)(Pbf + (size_t)row * FD + lane * 4) = f2bf4(p0);
  *(ushort4*)(Pbf + (size_t)row * FD + 256 + lane * 4) = f2bf4(p1);

  float dot = a0.x * p0.x + a0.y * p0.y + a0.z * p0.z + a0.w * p0.w +
              a1.x * p1.x + a1.y * p1.y + a1.z * p1.z + a1.w * p1.w;
  float na = a0.x * a0.x + a0.y * a0.y + a0.z * a0.z + a0.w * a0.w +
             a1.x * a1.x + a1.y * a1.y + a1.z * a1.z + a1.w * a1.w;
  float nb = p0.x * p0.x + p0.y * p0.y + p0.z * p0.z + p0.w * p0.w +
             p1.x * p1.x + p1.y * p1.y + p1.z * p1.z + p1.w * p1.w;
#pragma unroll
  for (int off = 32; off; off >>= 1) {
    dot += __shfl_xor(dot, off);
    na += __shfl_xor(na, off);
    nb += __shfl_xor(nb, off);
  }
  if (lane == 0) {
    dpos[row] = dot / fmaxf(sqrtf(na) * sqrtf(nb), 1e-8f);
    const float* pp = velo_pts + ((size_t)b * NP + ai) * 3;
    float x = pp[0], y = pp[1], z = pp[2];
    pts4[row] = make_float4(x, y, z, x * x + y * y + z * z);
  }
}

// ---------------------------------------------------------------------------
// Kernel 2: MFMA bf16 GEMM 128x128, T3-min 2-phase pipeline (dbuf LDS,
// STAGE(t+1) before compute(t), one barrier/iter), global_load_lds(16B),
// linear LDS + both-sides XOR swizzle. Swapped-operand MFMA so row-LSE is
// in-lane: acc[n][m] = mfma(bfr[n], af[m]) -> lane holds D[s = m*16+(lane&15),
// t = n*16+(lane>>4)*4+reg]. grid = (16,16,BS) x 256.
// ---------------------------------------------------------------------------
__global__ __launch_bounds__(256) void tile_k(
    const unsigned short* __restrict__ Abf, const unsigned short* __restrict__ Pbf,
    const float4* __restrict__ pts4,
    float* __restrict__ maxs, float* __restrict__ sums)
{
  __shared__ unsigned short As[2][8192];  // 16 KB per buffer, row = 128 B
  __shared__ unsigned short Bs[2][8192];

  const int ctile = blockIdx.x, stile = blockIdx.y, b = blockIdx.z;
  const int s0 = stile * 128, c0 = ctile * 128;
  const int tid = threadIdx.x;
  const int wid = tid >> 6, lane = tid & 63;
  const int wr = wid >> 1, wc = wid & 1;  // wave -> 64x64 quadrant
  const int cg = lane >> 4, cr = lane & 15;

  const char* Ab = (const char*)(Abf + ((size_t)b * SM + s0) * FD);
  const char* Bb = (const char*)(Pbf + ((size_t)b * SM + c0) * FD);

  // staging geometry: chunk = 8 rows x 128 B; inverse swizzle on global src
  int srow[4], soff[4];
#pragma unroll
  for (int i = 0; i < 4; i++) {
    const int L = (wid * 4 + i) * 1024 + lane * 16;
    srow[i] = L >> 7;
    soff[i] = (L & 127) ^ ((srow[i] & 7) << 4);
  }

#define STAGE(buf, kk)                                                         \
  do {                                                                         \
    _Pragma("unroll") for (int i = 0; i < 4; i++) {                            \
      const int chunk = wid * 4 + i;                                           \
      __builtin_amdgcn_global_load_lds(                                        \
          (const __attribute__((address_space(1))) void*)(                     \
              Ab + ((size_t)srow[i] << 10) + (kk) + soff[i]),                  \
          (__attribute__((address_space(3))) void*)(&As[buf][chunk * 512]),    \
          16, 0, 0);                                                           \
      __builtin_amdgcn_global_load_lds(                                        \
          (const __attribute__((address_space(1))) void*)(                     \
              Bb + ((size_t)srow[i] << 10) + (kk) + soff[i]),                  \
          (__attribute__((address_space(3))) void*)(&Bs[buf][chunk * 512]),    \
          16, 0, 0);                                                           \
    }                                                                          \
  } while (0)

  f32x4 acc[4][4];  // [n][m]
#pragma unroll
  for (int n = 0; n < 4; n++)
#pragma unroll
    for (int m = 0; m < 4; m++) acc[n][m] = (f32x4){0.f, 0.f, 0.f, 0.f};

  STAGE(0, 0);
  __syncthreads();  // drain prologue loads

  for (int t = 0; t < 8; ++t) {
    if (t < 7) STAGE((t + 1) & 1, (t + 1) * 128);
    const unsigned short* Asb = As[t & 1];
    const unsigned short* Bsb = Bs[t & 1];
#pragma unroll
    for (int ks = 0; ks < 2; ks++) {
      short8 af[4], bfr[4];
#pragma unroll
      for (int m = 0; m < 4; m++) {
        const int r = wr * 64 + m * 16 + cr;
        const int x = (ks * 64 + cg * 16) ^ ((r & 7) << 4);
        af[m] = *(const short8*)((const char*)Asb + r * 128 + x);
      }
#pragma unroll
      for (int n = 0; n < 4; n++) {
        const int r = wc * 64 + n * 16 + cr;
        const int x = (ks * 64 + cg * 16) ^ ((r & 7) << 4);
        bfr[n] = *(const short8*)((const char*)Bsb + r * 128 + x);
      }
#pragma unroll
      for (int n = 0; n < 4; n++)
#pragma unroll
        for (int m = 0; m < 4; m++)
          acc[n][m] = __builtin_amdgcn_mfma_f32_16x16x32_bf16(bfr[n], af[m],
                                                              acc[n][m], 0, 0, 0);
    }
    if (t < 7) __syncthreads();  // drains STAGE(t+1) loads (vmcnt 0) + barrier
  }

  // ---- epilogue: in-lane row LSE (lane owns 16 elements of row s per m) ----
  const float4* rpg = pts4 + (size_t)b * SM + s0 + wr * 64;
  const float4* cpg = pts4 + (size_t)b * SM + c0 + wc * 64;
  float4 rv[4];
#pragma unroll
  for (int m = 0; m < 4; m++) rv[m] = rpg[m * 16 + cr];

  float mx[4] = {-INFINITY, -INFINITY, -INFINITY, -INFINITY};
#pragma unroll
  for (int n = 0; n < 4; n++) {
#pragma unroll
    for (int reg = 0; reg < 4; reg++) {
      float4 cv = cpg[n * 16 + cg * 4 + reg];
#pragma unroll
      for (int m = 0; m < 4; m++) {
        float dot = rv[m].x * cv.x + rv[m].y * cv.y + rv[m].z * cv.z;
        float d2 = rv[m].w + cv.w - 2.f * dot;
        float l = (d2 > 25.f) ? acc[n][m][reg] * LOG2E10 : -INFINITY;
        acc[n][m][reg] = l;
        mx[m] = fmaxf(mx[m], l);
      }
    }
  }
  float mxc[4], sm[4];
#pragma unroll
  for (int m = 0; m < 4; m++) {
    mx[m] = fmaxf(mx[m], __shfl_xor(mx[m], 16));
    mx[m] = fmaxf(mx[m], __shfl_xor(mx[m], 32));
    mxc[m] = fmaxf(mx[m], -1e37f);  // finite subtrahend even if row all-masked
    sm[m] = 0.f;
  }
#pragma unroll
  for (int n = 0; n < 4; n++)
#pragma unroll
    for (int reg = 0; reg < 4; reg++)
#pragma unroll
      for (int m = 0; m < 4; m++)
        sm[m] += exp2f(acc[n][m][reg] - mxc[m]);  // exp2(-inf)=0
#pragma unroll
  for (int m = 0; m < 4; m++) {
    sm[m] += __shfl_xor(sm[m], 16);
    sm[m] += __shfl_xor(sm[m], 32);
  }
  if (cg == 0) {
    const int ct32 = ctile * 2 + wc;
    size_t base = ((size_t)ct32 * BS + b) * SM + s0 + wr * 64;
#pragma unroll
    for (int m = 0; m < 4; m++) {
      maxs[base + m * 16 + cr] = mx[m];
      sums[base + m * 16 + cr] = sm[m];
    }
  }
#undef STAGE
}

// ---------------------------------------------------------------------------
// Kernel 3: per-row LSE merge + loss, per-block f64 partial (32 blocks)
// ---------------------------------------------------------------------------
__global__ __launch_bounds__(256) void rowloss_k(
    const float* __restrict__ dpos, const float* __restrict__ maxs,
    const float* __restrict__ sums, double* __restrict__ partial)
{
  const int r = blockIdx.x * 256 + threadIdx.x;
  float l0 = dpos[r] * LOG2E10;
  float M = l0;
#pragma unroll 8
  for (int c = 0; c < 32; c++) M = fmaxf(M, maxs[(size_t)c * BS * SM + r]);
  float s = exp2f(l0 - M);
#pragma unroll 8
  for (int c = 0; c < 32; c++) {
    float mc = maxs[(size_t)c * BS * SM + r];
    float sc = sums[(size_t)c * BS * SM + r];
    s += sc * exp2f(mc - M);  // mc=-inf -> sc=0, exp2=0 -> 0 (no nan)
  }
  double v = (double)(LN2 * (M + log2f(s) - l0));
#pragma unroll
  for (int off = 32; off; off >>= 1) v += __shfl_down(v, off);
  __shared__ double red[4];
  if ((threadIdx.x & 63) == 0) red[threadIdx.x >> 6] = v;
  __syncthreads();
  if (threadIdx.x == 0)
    partial[blockIdx.x] = red[0] + red[1] + red[2] + red[3];
}

// ---------------------------------------------------------------------------
// Kernel 4: final mean over 32 partials (1 tiny block)
// ---------------------------------------------------------------------------
__global__ __launch_bounds__(64) void final_k(const double* __restrict__ partial,
                                              float* __restrict__ out)
{
  const int t = threadIdx.x;
  double v = (t < 32) ? partial[t] : 0.0;
#pragma unroll
  for (int off = 32; off; off >>= 1) v += __shfl_down(v, off);
  if (t == 0) out[0] = (float)(v / (double)(BS * SM));
}

// ---------------------------------------------------------------------------
extern "C" void kernel_launch(void* const* d_in, const int* in_sizes, int n_in,
                              void* d_out, int out_size, void* d_ws, size_t ws_size,
                              hipStream_t stream)
{
  const float* velo_feat = (const float*)d_in[0];
  const float* velo_pts  = (const float*)d_in[1];
  const float* ref_feat  = (const float*)d_in[2];
  const int*   matches   = (const int*)d_in[3];

  // ws layout: Abf(8MB) | Pbf(8MB) | pts4(128K) | dpos(32K) | maxs(1M) | sums(1M) | partial
  char* ws = (char*)d_ws;
  const size_t NBF = (size_t)BS * SM * FD * 2;
  unsigned short* Abf = (unsigned short*)ws;
  unsigned short* Pbf = (unsigned short*)(ws + NBF);
  float4* pts4 = (float4*)(ws + 2 * NBF);
  float*  dpos = (float*)(ws + 2 * NBF + (size_t)BS * SM * 16);
  float*  maxs = (float*)(ws + 2 * NBF + (size_t)BS * SM * 20);
  float*  sums = (float*)(ws + 2 * NBF + (size_t)BS * SM * 20 + (size_t)32 * BS * SM * 4);
  double* partial = (double*)(ws + 2 * NBF + (size_t)BS * SM * 20 + (size_t)64 * BS * SM * 4);

  stats_k<<<BS * SM / 4, 256, 0, stream>>>(velo_feat, velo_pts, ref_feat,
                                           matches, pts4, dpos, Abf, Pbf);
  tile_k<<<dim3(16, 16, BS), 256, 0, stream>>>(Abf, Pbf, pts4, maxs, sums);
  rowloss_k<<<BS * SM / 256, 256, 0, stream>>>(dpos, maxs, sums, partial);
  final_k<<<1, 64, 0, stream>>>(partial, (float*)d_out);
}

// Round 7
// 71.825 us; speedup vs baseline: 7.8509x; 1.0222x over previous
//
#include <hip/hip_runtime.h>
#include <hip/hip_bf16.h>
#include <cmath>

#define BS 4
#define NP 8192
#define FD 512
#define SM 2048
#define LOG2E10 14.4269504088896340736f  // 10 * log2(e)  (tau=0.1 folded)
#define LN2 0.6931471805599453f

typedef __attribute__((ext_vector_type(8))) short short8;
typedef __attribute__((ext_vector_type(4))) float f32x4;

static __device__ __forceinline__ unsigned short f2bf(float f) {
  unsigned u = __float_as_uint(f);
  unsigned r = u + 0x7fffu + ((u >> 16) & 1u);  // RTNE
  return (unsigned short)(r >> 16);
}
static __device__ __forceinline__ ushort4 f2bf4(float4 v) {
  ushort4 o;
  o.x = f2bf(v.x); o.y = f2bf(v.y); o.z = f2bf(v.z); o.w = f2bf(v.w);
  return o;
}

// ---------------------------------------------------------------------------
// Kernel 1: 1 wave per match row — gather, cos-sim, pts(+|p|^2), bf16 copies
// ---------------------------------------------------------------------------
__global__ __launch_bounds__(256) void stats_k(
    const float* __restrict__ velo_feat, const float* __restrict__ velo_pts,
    const float* __restrict__ ref_feat, const int* __restrict__ matches,
    float4* __restrict__ pts4, float* __restrict__ dpos,
    unsigned short* __restrict__ Abf, unsigned short* __restrict__ Pbf)
{
  const int row = blockIdx.x * 4 + (threadIdx.x >> 6);  // b*SM + s
  const int lane = threadIdx.x & 63;
  const int b = row >> 11;  // / SM
  const int ai = matches[2 * row + 0];
  const int pi = matches[2 * row + 1];

  const float4* ar = (const float4*)(velo_feat + ((size_t)b * NP + ai) * FD);
  const float4* pr = (const float4*)(ref_feat + ((size_t)b * NP + pi) * FD);
  float4 a0 = ar[lane], a1 = ar[lane + 64];
  float4 p0 = pr[lane], p1 = pr[lane + 64];

  *(ushort4*)(Abf + (size_t)row * FD + lane * 4) = f2bf4(a0);
  *(ushort4*)(Abf + (size_t)row * FD + 256 + lane * 4) = f2bf4(a1);
  *(ushort4*)(Pbf + (size_t)row * FD + lane * 4) = f2bf4(p0);
  *(ushort4*)(Pbf + (size_t)row * FD + 256 + lane * 4) = f2bf4(p1);

  float dot = a0.x * p0.x + a0.y * p0.y + a0.z * p0.z + a0.w * p0.w +
              a1.x * p1.x + a1.y * p1.y + a1.z * p1.z + a1.w * p1.w;
  float na = a0.x * a0.x + a0.y * a0.y + a0.z * a0.z + a0.w * a0.w +
             a1.x * a1.x + a1.y * a1.y + a1.z * a1.z + a1.w * a1.w;
  float nb = p0.x * p0.x + p0.y * p0.y + p0.z * p0.z + p0.w * p0.w +
             p1.x * p1.x + p1.y * p1.y + p1.z * p1.z + p1.w * p1.w;
#pragma unroll
  for (int off = 32; off; off >>= 1) {
    dot += __shfl_xor(dot, off);
    na += __shfl_xor(na, off);
    nb += __shfl_xor(nb, off);
  }
  if (lane == 0) {
    dpos[row] = dot / fmaxf(sqrtf(na) * sqrtf(nb), 1e-8f);
    const float* pp = velo_pts + ((size_t)b * NP + ai) * 3;
    float x = pp[0], y = pp[1], z = pp[2];
    pts4[row] = make_float4(x, y, z, x * x + y * y + z * z);
  }
}

// ---------------------------------------------------------------------------
// Kernel 2: MFMA bf16 GEMM 128x128.
//  - counted-vmcnt double-buffer pipeline: STAGE(t+1); vmcnt(8); barrier;
//    compute(t); barrier  -> next tile's 8 DMA loads stay in flight across
//    the barriers and hide under compute (T3/T4).
//  - XCD-aware block swizzle (1024 blocks, %8==0 -> simple bijection): each
//    XCD gets a contiguous half-batch slab, L2 working set ~3MB.
//  - global_load_lds(16B), linear LDS + both-sides XOR swizzle.
//  - swapped-operand MFMA -> row-LSE is in-lane (lane owns 16 cols of a row).
// grid = 1024 x 256.
// ---------------------------------------------------------------------------
__global__ __launch_bounds__(256) void tile_k(
    const unsigned short* __restrict__ Abf, const unsigned short* __restrict__ Pbf,
    const float4* __restrict__ pts4,
    float* __restrict__ maxs, float* __restrict__ sums)
{
  __shared__ unsigned short As[2][8192];  // 16 KB per buffer, row = 128 B
  __shared__ unsigned short Bs[2][8192];

  // XCD swizzle: orig%8 = XCD -> give it a contiguous logical slab
  const int wg = ((blockIdx.x & 7) << 7) + (blockIdx.x >> 3);
  const int b = wg >> 8;            // 256 blocks per batch
  const int stile = (wg >> 4) & 15; // slab walks ctile fastest (A-slice reuse)
  const int ctile = wg & 15;

  const int s0 = stile * 128, c0 = ctile * 128;
  const int tid = threadIdx.x;
  const int wid = tid >> 6, lane = tid & 63;
  const int wr = wid >> 1, wc = wid & 1;  // wave -> 64x64 quadrant
  const int cg = lane >> 4, cr = lane & 15;

  const char* Ab = (const char*)(Abf + ((size_t)b * SM + s0) * FD);
  const char* Bb = (const char*)(Pbf + ((size_t)b * SM + c0) * FD);

  // staging geometry: chunk = 8 rows x 128 B; inverse swizzle on global src
  int srow[4], soff[4];
#pragma unroll
  for (int i = 0; i < 4; i++) {
    const int L = (wid * 4 + i) * 1024 + lane * 16;
    srow[i] = L >> 7;
    soff[i] = (L & 127) ^ ((srow[i] & 7) << 4);
  }

#define STAGE(buf, kk)                                                         \
  do {                                                                         \
    _Pragma("unroll") for (int i = 0; i < 4; i++) {                            \
      const int chunk = wid * 4 + i;                                           \
      __builtin_amdgcn_global_load_lds(                                        \
          (const __attribute__((address_space(1))) void*)(                     \
              Ab + ((size_t)srow[i] << 10) + (kk) + soff[i]),                  \
          (__attribute__((address_space(3))) void*)(&As[buf][chunk * 512]),    \
          16, 0, 0);                                                           \
      __builtin_amdgcn_global_load_lds(                                        \
          (const __attribute__((address_space(1))) void*)(                     \
              Bb + ((size_t)srow[i] << 10) + (kk) + soff[i]),                  \
          (__attribute__((address_space(3))) void*)(&Bs[buf][chunk * 512]),    \
          16, 0, 0);                                                           \
    }                                                                          \
  } while (0)

  f32x4 acc[4][4];  // [n][m]
#pragma unroll
  for (int n = 0; n < 4; n++)
#pragma unroll
    for (int m = 0; m < 4; m++) acc[n][m] = (f32x4){0.f, 0.f, 0.f, 0.f};

  // compute one K-tile (BK=64) from buffer `buf`
  auto compute = [&](int buf) {
#pragma unroll
    for (int ks = 0; ks < 2; ks++) {
      short8 af[4], bfr[4];
#pragma unroll
      for (int m = 0; m < 4; m++) {
        const int r = wr * 64 + m * 16 + cr;
        const int x = (ks * 64 + cg * 16) ^ ((r & 7) << 4);
        af[m] = *(const short8*)((const char*)As[buf] + r * 128 + x);
      }
#pragma unroll
      for (int n = 0; n < 4; n++) {
        const int r = wc * 64 + n * 16 + cr;
        const int x = (ks * 64 + cg * 16) ^ ((r & 7) << 4);
        bfr[n] = *(const short8*)((const char*)Bs[buf] + r * 128 + x);
      }
#pragma unroll
      for (int n = 0; n < 4; n++)
#pragma unroll
        for (int m = 0; m < 4; m++)
          acc[n][m] = __builtin_amdgcn_mfma_f32_16x16x32_bf16(bfr[n], af[m],
                                                              acc[n][m], 0, 0, 0);
    }
  };

  STAGE(0, 0);  // prologue: 8 loads in flight
#pragma unroll 1
  for (int t = 0; t < 7; ++t) {
    STAGE((t + 1) & 1, (t + 1) * 128);            // +8 loads (now <=16)
    asm volatile("s_waitcnt vmcnt(8)" ::: "memory");  // STAGE(t) landed
    asm volatile("s_barrier" ::: "memory");           // ... for ALL waves
    compute(t & 1);
    asm volatile("s_barrier" ::: "memory");  // all reads done before t+2 overwrite
  }
  asm volatile("s_waitcnt vmcnt(0)" ::: "memory");
  asm volatile("s_barrier" ::: "memory");
  compute(1);  // t=7

  // ---- epilogue: in-lane row LSE (lane owns 16 elements of row s per m) ----
  const float4* rpg = pts4 + (size_t)b * SM + s0 + wr * 64;
  const float4* cpg = pts4 + (size_t)b * SM + c0 + wc * 64;
  float4 rv[4];
#pragma unroll
  for (int m = 0; m < 4; m++) rv[m] = rpg[m * 16 + cr];

  float mx[4] = {-INFINITY, -INFINITY, -INFINITY, -INFINITY};
#pragma unroll
  for (int n = 0; n < 4; n++) {
#pragma unroll
    for (int reg = 0; reg < 4; reg++) {
      float4 cv = cpg[n * 16 + cg * 4 + reg];
#pragma unroll
      for (int m = 0; m < 4; m++) {
        float dot = rv[m].x * cv.x + rv[m].y * cv.y + rv[m].z * cv.z;
        float d2 = rv[m].w + cv.w - 2.f * dot;
        float l = (d2 > 25.f) ? acc[n][m][reg] * LOG2E10 : -INFINITY;
        acc[n][m][reg] = l;
        mx[m] = fmaxf(mx[m], l);
      }
    }
  }
  float mxc[4], sm[4];
#pragma unroll
  for (int m = 0; m < 4; m++) {
    mx[m] = fmaxf(mx[m], __shfl_xor(mx[m], 16));
    mx[m] = fmaxf(mx[m], __shfl_xor(mx[m], 32));
    mxc[m] = fmaxf(mx[m], -1e37f);  // finite subtrahend even if row all-masked
    sm[m] = 0.f;
  }
#pragma unroll
  for (int n = 0; n < 4; n++)
#pragma unroll
    for (int reg = 0; reg < 4; reg++)
#pragma unroll
      for (int m = 0; m < 4; m++)
        sm[m] += exp2f(acc[n][m][reg] - mxc[m]);  // exp2(-inf)=0
#pragma unroll
  for (int m = 0; m < 4; m++) {
    sm[m] += __shfl_xor(sm[m], 16);
    sm[m] += __shfl_xor(sm[m], 32);
  }
  if (cg == 0) {
    const int ct32 = ctile * 2 + wc;
    size_t base = ((size_t)ct32 * BS + b) * SM + s0 + wr * 64;
#pragma unroll
    for (int m = 0; m < 4; m++) {
      maxs[base + m * 16 + cr] = mx[m];
      sums[base + m * 16 + cr] = sm[m];
    }
  }
#undef STAGE
}

// ---------------------------------------------------------------------------
// Kernel 3: per-row LSE merge + loss, per-block f64 partial (32 blocks)
// ---------------------------------------------------------------------------
__global__ __launch_bounds__(256) void rowloss_k(
    const float* __restrict__ dpos, const float* __restrict__ maxs,
    const float* __restrict__ sums, double* __restrict__ partial)
{
  const int r = blockIdx.x * 256 + threadIdx.x;
  float l0 = dpos[r] * LOG2E10;
  float M = l0;
#pragma unroll 8
  for (int c = 0; c < 32; c++) M = fmaxf(M, maxs[(size_t)c * BS * SM + r]);
  float s = exp2f(l0 - M);
#pragma unroll 8
  for (int c = 0; c < 32; c++) {
    float mc = maxs[(size_t)c * BS * SM + r];
    float sc = sums[(size_t)c * BS * SM + r];
    s += sc * exp2f(mc - M);  // mc=-inf -> sc=0, exp2=0 -> 0 (no nan)
  }
  double v = (double)(LN2 * (M + log2f(s) - l0));
#pragma unroll
  for (int off = 32; off; off >>= 1) v += __shfl_down(v, off);
  __shared__ double red[4];
  if ((threadIdx.x & 63) == 0) red[threadIdx.x >> 6] = v;
  __syncthreads();
  if (threadIdx.x == 0)
    partial[blockIdx.x] = red[0] + red[1] + red[2] + red[3];
}

// ---------------------------------------------------------------------------
// Kernel 4: final mean over 32 partials (1 tiny block)
// ---------------------------------------------------------------------------
__global__ __launch_bounds__(64) void final_k(const double* __restrict__ partial,
                                              float* __restrict__ out)
{
  const int t = threadIdx.x;
  double v = (t < 32) ? partial[t] : 0.0;
#pragma unroll
  for (int off = 32; off; off >>= 1) v += __shfl_down(v, off);
  if (t == 0) out[0] = (float)(v / (double)(BS * SM));
}

// ---------------------------------------------------------------------------
extern "C" void kernel_launch(void* const* d_in, const int* in_sizes, int n_in,
                              void* d_out, int out_size, void* d_ws, size_t ws_size,
                              hipStream_t stream)
{
  const float* velo_feat = (const float*)d_in[0];
  const float* velo_pts  = (const float*)d_in[1];
  const float* ref_feat  = (const float*)d_in[2];
  const int*   matches   = (const int*)d_in[3];

  // ws layout: Abf(8MB) | Pbf(8MB) | pts4(128K) | dpos(32K) | maxs(1M) | sums(1M) | partial
  char* ws = (char*)d_ws;
  const size_t NBF = (size_t)BS * SM * FD * 2;
  unsigned short* Abf = (unsigned short*)ws;
  unsigned short* Pbf = (unsigned short*)(ws + NBF);
  float4* pts4 = (float4*)(ws + 2 * NBF);
  float*  dpos = (float*)(ws + 2 * NBF + (size_t)BS * SM * 16);
  float*  maxs = (float*)(ws + 2 * NBF + (size_t)BS * SM * 20);
  float*  sums = (float*)(ws + 2 * NBF + (size_t)BS * SM * 20 + (size_t)32 * BS * SM * 4);
  double* partial = (double*)(ws + 2 * NBF + (size_t)BS * SM * 20 + (size_t)64 * BS * SM * 4);

  stats_k<<<BS * SM / 4, 256, 0, stream>>>(velo_feat, velo_pts, ref_feat,
                                           matches, pts4, dpos, Abf, Pbf);
  tile_k<<<1024, 256, 0, stream>>>(Abf, Pbf, pts4, maxs, sums);
  rowloss_k<<<BS * SM / 256, 256, 0, stream>>>(dpos, maxs, sums, partial);
  final_k<<<1, 64, 0, stream>>>(partial, (float*)d_out);
}